// Round 11
// baseline (81.260 us; speedup 1.0000x reference)
//
#include <hip/hip_runtime.h>
#include <hip/hip_bf16.h>

typedef __attribute__((ext_vector_type(4))) float f32x4;
typedef __attribute__((ext_vector_type(8))) short short8;

#define B_ 16
#define C_ 64
#define H_ 128
#define W_ 128
#define Z_ 128
#define HW_ (H_*W_)
#define IDXN (C_*C_*9)    // 36864 weight elements per sample
#define NT 18             // K=576 -> 18 MFMA k-steps of 32

__device__ __forceinline__ unsigned short f2bf(float f) {
  __hip_bfloat16 h = __float2bfloat16(f);
  return *reinterpret_cast<unsigned short*>(&h);
}

// ---------------- kernel 1: weight generation, pre-swizzled to MFMA fragment layout
__global__ __launch_bounds__(256) void wgen_k(
    const float* __restrict__ z, const float* __restrict__ gw,
    const float* __restrict__ gb, unsigned short* __restrict__ wfrag) {
  __shared__ __align__(16) float zs[B_*Z_];   // 8 KB
  int t = threadIdx.x;
#pragma unroll
  for (int i = 0; i < 8; ++i) zs[i*256 + t] = z[i*256 + t];
  __syncthreads();
  int lane = t & 63, bg = t >> 6;
  int b0 = bg*4;
  int idx0 = blockIdx.x*128 + lane;           // stream 0: idx0, stream 1: idx0+64
  float acc[4][2];
  float bv0 = gb[idx0], bv1 = gb[idx0 + 64];
#pragma unroll
  for (int bi = 0; bi < 4; ++bi) { acc[bi][0] = bv0; acc[bi][1] = bv1; }

  for (int z0 = 0; z0 < Z_; z0 += 4) {
    float ga[4], gbv[4];
#pragma unroll
    for (int zi = 0; zi < 4; ++zi) {
      ga[zi]  = gw[(size_t)(z0+zi)*IDXN + idx0];
      gbv[zi] = gw[(size_t)(z0+zi)*IDXN + idx0 + 64];
    }
#pragma unroll
    for (int bi = 0; bi < 4; ++bi) {
      f32x4 zq = *reinterpret_cast<const f32x4*>(&zs[(b0+bi)*Z_ + z0]);
      acc[bi][0] = fmaf(zq[0], ga[0], fmaf(zq[1], ga[1], fmaf(zq[2], ga[2], fmaf(zq[3], ga[3], acc[bi][0]))));
      acc[bi][1] = fmaf(zq[0], gbv[0], fmaf(zq[1], gbv[1], fmaf(zq[2], gbv[2], fmaf(zq[3], gbv[3], acc[bi][1]))));
    }
  }
#pragma unroll
  for (int ni = 0; ni < 2; ++ni) {
    int idx = idx0 + ni*64;
    int kw = idx % 3, r1 = idx/3;
    int kh = r1 % 3, r2 = r1/3;
    int ci = r2 & 63, co = r2 >> 6;
    int k = (kh*3 + kw)*C_ + ci;
    int ts = k >> 5, kin = k & 31;
    int lm = (co & 15) | ((kin >> 3) << 4);
    int j = kin & 7, m = co >> 4;
    int base = ((ts*4 + m)*64 + lm)*8 + j;
#pragma unroll
    for (int bi = 0; bi < 4; ++bi)
      wfrag[(size_t)(b0+bi)*(NT*4*64*8) + base] = f2bf(acc[bi][ni]);
  }
}

// ---------------- kernel 2: REAL conv (R10 best-known, unchanged) ----------------
__global__ __launch_bounds__(512, 4) void conv_k(
    const float* __restrict__ x,
    const unsigned short* __restrict__ wfrag,
    float* __restrict__ out) {
  __shared__ __align__(16) unsigned char xs[4*130*128];   // 66560 B; reused as obuf[64][260] f32
  int orig = blockIdx.x;
  int blk = (orig & 7)*128 + (orig >> 3);   // bijective XCD swizzle: 1024 = 8*128
  int b = blk >> 6;
  int h0 = (blk & 63)*2;
  int tid = threadIdx.x;
  int v = tid >> 6, lane = tid & 63;

  {
    int r = v >> 1, hf = v & 1;
    int hh = h0 - 1 + r;
    bool hv = (hh >= 0) & (hh < H_);
    unsigned char* ldsrow = xs + r*(130*128);
    if (hv) {
      if (lane < 8) {
        int s = hf ? (1032 + lane) : lane;
        uint4 zv; zv.x = 0; zv.y = 0; zv.z = 0; zv.w = 0;
        *reinterpret_cast<uint4*>(ldsrow + s*16) = zv;
      }
      const float* xrow = x + (((size_t)b*C_)*H_ + hh)*W_;
      int w0 = 2*lane, col0 = w0 + 1, col1 = w0 + 2;
      int g = lane >> 3;
#pragma unroll
      for (int i = 0; i < 4; ++i) {
        int chunk = (hf*4 + i + g) & 7;
        float2 v2[8];
#pragma unroll
        for (int j = 0; j < 8; ++j)
          v2[j] = *reinterpret_cast<const float2*>(xrow + (size_t)(chunk*8 + j)*HW_ + w0);
        uint4 o0, o1;
        unsigned short* s0 = reinterpret_cast<unsigned short*>(&o0);
        unsigned short* s1 = reinterpret_cast<unsigned short*>(&o1);
#pragma unroll
        for (int j = 0; j < 8; ++j) { s0[j] = f2bf(v2[j].x); s1[j] = f2bf(v2[j].y); }
        int a0 = col0*128 + (((chunk ^ col0) & 7) << 4);
        int a1 = col1*128 + (((chunk ^ col1) & 7) << 4);
        *reinterpret_cast<uint4*>(ldsrow + a0) = o0;
        *reinterpret_cast<uint4*>(ldsrow + a1) = o1;
      }
    } else {
      uint4 zv; zv.x = 0; zv.y = 0; zv.z = 0; zv.w = 0;
#pragma unroll
      for (int it = 0; it < 9; ++it) {
        int di = it*64 + lane;
        if (di < 520) *reinterpret_cast<uint4*>(ldsrow + (hf*520 + di)*16) = zv;
      }
    }
  }

  int l15 = lane & 15, lhi = lane >> 4;
  int phr = v >> 2, pw0 = ((v >> 1) & 1)*64;
  int mt0 = (v & 1)*2;
  const unsigned short* wb = wfrag + (size_t)b*(NT*4*64*8);

  short8 wf0 = *reinterpret_cast<const short8*>(wb + (((mt0 + 0)*64 + lane)*8));
  short8 wf1 = *reinterpret_cast<const short8*>(wb + (((mt0 + 1)*64 + lane)*8));

  __syncthreads();

  f32x4 acc[4][2];
#pragma unroll
  for (int mp = 0; mp < 4; ++mp)
#pragma unroll
    for (int nc = 0; nc < 2; ++nc)
      acc[mp][nc] = (f32x4){0.f, 0.f, 0.f, 0.f};

#pragma unroll
  for (int t = 0; t < NT; ++t) {
    int kk = t >> 1, kh = kk/3, kw = kk - 3*kh, half = t & 1;
    short8 nf0, nf1;
    if (t + 1 < NT) {
      nf0 = *reinterpret_cast<const short8*>(wb + ((((t+1)*4 + mt0 + 0)*64 + lane)*8));
      nf1 = *reinterpret_cast<const short8*>(wb + ((((t+1)*4 + mt0 + 1)*64 + lane)*8));
    }
    int chunk = half*4 + lhi;
    short8 xa[4];
#pragma unroll
    for (int mp = 0; mp < 4; ++mp) {
      int col = pw0 + mp*16 + l15 + kw;
      int addr = ((phr + kh)*130 + col)*128 + (((chunk ^ col) & 7) << 4);
      xa[mp] = *reinterpret_cast<const short8*>(&xs[addr]);
    }
#pragma unroll
    for (int mp = 0; mp < 4; ++mp) {
      acc[mp][0] = __builtin_amdgcn_mfma_f32_16x16x32_bf16(xa[mp], wf0, acc[mp][0], 0, 0, 0);
      acc[mp][1] = __builtin_amdgcn_mfma_f32_16x16x32_bf16(xa[mp], wf1, acc[mp][1], 0, 0, 0);
    }
    wf0 = nf0; wf1 = nf1;
  }

  __syncthreads();
  float* obuf = reinterpret_cast<float*>(xs);
#pragma unroll
  for (int nc = 0; nc < 2; ++nc) {
    int co = (mt0 + nc)*16 + l15;
#pragma unroll
    for (int mp = 0; mp < 4; ++mp) {
      int px = pw0 + mp*16 + lhi*4;
      *reinterpret_cast<f32x4*>(&obuf[co*260 + phr*128 + px]) = acc[mp][nc];
    }
  }
  __syncthreads();
  {
    float* ob = out + ((size_t)b*C_)*HW_ + (size_t)h0*W_;
#pragma unroll
    for (int i = 0; i < 8; ++i) {
      int co = i*8 + v;
      f32x4 val = *reinterpret_cast<const f32x4*>(&obuf[co*260 + lane*4]);
      *reinterpret_cast<f32x4*>(ob + (size_t)co*HW_ + lane*4) = val;
    }
  }
}

// ---------------- PROBE A: staging phase only (x reads + pack + swizzled ds_write)
__global__ __launch_bounds__(512, 4) void probe_stage_k(
    const float* __restrict__ x, uint4* __restrict__ ws) {
  __shared__ __align__(16) unsigned char xs[4*130*128];
  int orig = blockIdx.x;
  int blk = (orig & 7)*128 + (orig >> 3);
  int b = blk >> 6;
  int h0 = (blk & 63)*2;
  int tid = threadIdx.x;
  int v = tid >> 6, lane = tid & 63;
  {
    int r = v >> 1, hf = v & 1;
    int hh = h0 - 1 + r;
    bool hv = (hh >= 0) & (hh < H_);
    unsigned char* ldsrow = xs + r*(130*128);
    if (hv) {
      if (lane < 8) {
        int s = hf ? (1032 + lane) : lane;
        uint4 zv; zv.x = 0; zv.y = 0; zv.z = 0; zv.w = 0;
        *reinterpret_cast<uint4*>(ldsrow + s*16) = zv;
      }
      const float* xrow = x + (((size_t)b*C_)*H_ + hh)*W_;
      int w0 = 2*lane, col0 = w0 + 1, col1 = w0 + 2;
      int g = lane >> 3;
#pragma unroll
      for (int i = 0; i < 4; ++i) {
        int chunk = (hf*4 + i + g) & 7;
        float2 v2[8];
#pragma unroll
        for (int j = 0; j < 8; ++j)
          v2[j] = *reinterpret_cast<const float2*>(xrow + (size_t)(chunk*8 + j)*HW_ + w0);
        uint4 o0, o1;
        unsigned short* s0 = reinterpret_cast<unsigned short*>(&o0);
        unsigned short* s1 = reinterpret_cast<unsigned short*>(&o1);
#pragma unroll
        for (int j = 0; j < 8; ++j) { s0[j] = f2bf(v2[j].x); s1[j] = f2bf(v2[j].y); }
        int a0 = col0*128 + (((chunk ^ col0) & 7) << 4);
        int a1 = col1*128 + (((chunk ^ col1) & 7) << 4);
        *reinterpret_cast<uint4*>(ldsrow + a0) = o0;
        *reinterpret_cast<uint4*>(ldsrow + a1) = o1;
      }
    } else {
      uint4 zv; zv.x = 0; zv.y = 0; zv.z = 0; zv.w = 0;
#pragma unroll
      for (int it = 0; it < 9; ++it) {
        int di = it*64 + lane;
        if (di < 520) *reinterpret_cast<uint4*>(ldsrow + (hf*520 + di)*16) = zv;
      }
    }
  }
  __syncthreads();
  // keep LDS live: one dependent read per thread -> 16 B to ws
  int slot = (tid*13) & 4095;   // < 4160 slots
  uint4 val = *reinterpret_cast<const uint4*>(&xs[slot*16]);
  ws[(size_t)blockIdx.x*512 + tid] = val;
}

// ---------------- PROBE B: K-loop + weight stream on zeroed LDS (no x reads, 16B/thread out)
__global__ __launch_bounds__(512, 4) void probe_kloop_k(
    const unsigned short* __restrict__ wfrag, f32x4* __restrict__ ws) {
  __shared__ __align__(16) unsigned char xs[4*130*128];
  int orig = blockIdx.x;
  int blk = (orig & 7)*128 + (orig >> 3);
  int b = blk >> 6;
  int tid = threadIdx.x;
  int v = tid >> 6, lane = tid & 63;
  // zero LDS: 4160 uint4 slots
  {
    uint4 zv; zv.x = 0; zv.y = 0; zv.z = 0; zv.w = 0;
#pragma unroll
    for (int i = 0; i < 9; ++i) {
      int di = i*512 + tid;
      if (di < 4160) *reinterpret_cast<uint4*>(&xs[di*16]) = zv;
    }
  }
  int l15 = lane & 15, lhi = lane >> 4;
  int phr = v >> 2, pw0 = ((v >> 1) & 1)*64;
  int mt0 = (v & 1)*2;
  const unsigned short* wb = wfrag + (size_t)b*(NT*4*64*8);
  short8 wf0 = *reinterpret_cast<const short8*>(wb + (((mt0 + 0)*64 + lane)*8));
  short8 wf1 = *reinterpret_cast<const short8*>(wb + (((mt0 + 1)*64 + lane)*8));
  __syncthreads();
  f32x4 acc[4][2];
#pragma unroll
  for (int mp = 0; mp < 4; ++mp)
#pragma unroll
    for (int nc = 0; nc < 2; ++nc)
      acc[mp][nc] = (f32x4){0.f, 0.f, 0.f, 0.f};
#pragma unroll
  for (int t = 0; t < NT; ++t) {
    int kk = t >> 1, kh = kk/3, kw = kk - 3*kh, half = t & 1;
    short8 nf0, nf1;
    if (t + 1 < NT) {
      nf0 = *reinterpret_cast<const short8*>(wb + ((((t+1)*4 + mt0 + 0)*64 + lane)*8));
      nf1 = *reinterpret_cast<const short8*>(wb + ((((t+1)*4 + mt0 + 1)*64 + lane)*8));
    }
    int chunk = half*4 + lhi;
    short8 xa[4];
#pragma unroll
    for (int mp = 0; mp < 4; ++mp) {
      int col = pw0 + mp*16 + l15 + kw;
      int addr = ((phr + kh)*130 + col)*128 + (((chunk ^ col) & 7) << 4);
      xa[mp] = *reinterpret_cast<const short8*>(&xs[addr]);
    }
#pragma unroll
    for (int mp = 0; mp < 4; ++mp) {
      acc[mp][0] = __builtin_amdgcn_mfma_f32_16x16x32_bf16(xa[mp], wf0, acc[mp][0], 0, 0, 0);
      acc[mp][1] = __builtin_amdgcn_mfma_f32_16x16x32_bf16(xa[mp], wf1, acc[mp][1], 0, 0, 0);
    }
    wf0 = nf0; wf1 = nf1;
  }
  f32x4 s = (f32x4){0.f,0.f,0.f,0.f};
#pragma unroll
  for (int mp = 0; mp < 4; ++mp)
#pragma unroll
    for (int nc = 0; nc < 2; ++nc)
      s += acc[mp][nc];
  ws[(size_t)blockIdx.x*512 + tid] = s;
}

__global__ void sentinel_k(float* out, int n) {
  int i = blockIdx.x*256 + threadIdx.x;
  if (i < n) out[i] = 1.0e6f;
}

extern "C" void kernel_launch(void* const* d_in, const int* in_sizes, int n_in,
                              void* d_out, int out_size, void* d_ws, size_t ws_size,
                              hipStream_t stream) {
  const float* x  = (const float*)d_in[0];
  const float* z  = (const float*)d_in[1];
  const float* gw = (const float*)d_in[2];
  const float* gb = (const float*)d_in[3];
  float* out = (float*)d_out;

  size_t wfrag_elems = (size_t)B_*IDXN;                   // bf16 elems
  size_t need = wfrag_elems*sizeof(unsigned short);
  if (ws_size < need) {
    sentinel_k<<<(out_size + 255)/256, 256, 0, stream>>>(out, out_size);
    return;
  }
  unsigned short* wfrag = (unsigned short*)d_ws;

  wgen_k <<<IDXN/128, 256, 0, stream>>>(z, gw, gb, wfrag);
  conv_k <<<B_*(H_/2), 512, 0, stream>>>(x, wfrag, out);

  // ---- diagnostic probes (write only to spare workspace; deterministic)
  if (ws_size >= (size_t)48*1024*1024) {
    uint4* ws1 = (uint4*)((char*)d_ws + (size_t)16*1024*1024);
    f32x4* ws2 = (f32x4*)((char*)d_ws + (size_t)32*1024*1024);
    probe_stage_k<<<B_*(H_/2), 512, 0, stream>>>(x, ws1);
    probe_kloop_k<<<B_*(H_/2), 512, 0, stream>>>(wfrag, ws2);
  }
}

// Round 12
// 50.573 us; speedup vs baseline: 1.6068x; 1.6068x over previous
//
#include <hip/hip_runtime.h>
#include <hip/hip_bf16.h>

typedef __attribute__((ext_vector_type(4))) float f32x4;
typedef __attribute__((ext_vector_type(8))) short short8;

#define B_ 16
#define C_ 64
#define H_ 128
#define W_ 128
#define Z_ 128
#define HW_ (H_*W_)
#define IDXN (C_*C_*9)    // 36864 weight elements per sample
#define NT 18             // K=576 -> 18 MFMA k-steps of 32

__device__ __forceinline__ unsigned short f2bf(float f) {
  __hip_bfloat16 h = __float2bfloat16(f);
  return *reinterpret_cast<unsigned short*>(&h);
}

// ---------------- kernel 1: weight generation, pre-swizzled to MFMA fragment layout
__global__ __launch_bounds__(256) void wgen_k(
    const float* __restrict__ z, const float* __restrict__ gw,
    const float* __restrict__ gb, unsigned short* __restrict__ wfrag) {
  __shared__ __align__(16) float zs[B_*Z_];   // 8 KB
  int t = threadIdx.x;
#pragma unroll
  for (int i = 0; i < 8; ++i) zs[i*256 + t] = z[i*256 + t];
  __syncthreads();
  int lane = t & 63, bg = t >> 6;
  int b0 = bg*4;
  int idx0 = blockIdx.x*128 + lane;           // stream 0: idx0, stream 1: idx0+64
  float acc[4][2];
  float bv0 = gb[idx0], bv1 = gb[idx0 + 64];
#pragma unroll
  for (int bi = 0; bi < 4; ++bi) { acc[bi][0] = bv0; acc[bi][1] = bv1; }

  for (int z0 = 0; z0 < Z_; z0 += 4) {
    float ga[4], gbv[4];
#pragma unroll
    for (int zi = 0; zi < 4; ++zi) {
      ga[zi]  = gw[(size_t)(z0+zi)*IDXN + idx0];
      gbv[zi] = gw[(size_t)(z0+zi)*IDXN + idx0 + 64];
    }
#pragma unroll
    for (int bi = 0; bi < 4; ++bi) {
      f32x4 zq = *reinterpret_cast<const f32x4*>(&zs[(b0+bi)*Z_ + z0]);
      acc[bi][0] = fmaf(zq[0], ga[0], fmaf(zq[1], ga[1], fmaf(zq[2], ga[2], fmaf(zq[3], ga[3], acc[bi][0]))));
      acc[bi][1] = fmaf(zq[0], gbv[0], fmaf(zq[1], gbv[1], fmaf(zq[2], gbv[2], fmaf(zq[3], gbv[3], acc[bi][1]))));
    }
  }
#pragma unroll
  for (int ni = 0; ni < 2; ++ni) {
    int idx = idx0 + ni*64;
    int kw = idx % 3, r1 = idx/3;
    int kh = r1 % 3, r2 = r1/3;
    int ci = r2 & 63, co = r2 >> 6;
    int k = (kh*3 + kw)*C_ + ci;
    int ts = k >> 5, kin = k & 31;
    int lm = (co & 15) | ((kin >> 3) << 4);
    int j = kin & 7, m = co >> 4;
    int base = ((ts*4 + m)*64 + lm)*8 + j;
#pragma unroll
    for (int bi = 0; bi < 4; ++bi)
      wfrag[(size_t)(b0+bi)*(NT*4*64*8) + base] = f2bf(acc[bi][ni]);
  }
}

// ---------------- kernel 2: persistent-band conv, 6-slot LDS ring, issue/commit pipeline
// grid 256 (1 block/CU), 512 thr = 8 waves. Block: sample b, 8-row band (4 pairs).
// LDS ring: xs[6 slots][130 cols][8 chunk-slots][16B]; slot(img row g) = (g-hbase+1) mod 6.
// Content: slot s at col holds ci-chunk s^(col&7) (verified layout, R5/R10 formulas verbatim).
// Per iter p: ISSUE loads rows(pair p+1) -> K-loop pair p (18 steps) -> store -> COMMIT -> barrier.
__global__ __launch_bounds__(512, 2) void conv_k(
    const float* __restrict__ x,
    const unsigned short* __restrict__ wfrag,
    float* __restrict__ out) {
  __shared__ __align__(16) unsigned char xs[6*130*128];   // 99840 B -> 1 block/CU
  int orig = blockIdx.x;
  int blk = (orig & 7)*32 + (orig >> 3);   // bijective XCD swizzle: 256 = 8*32
  int b = blk >> 4;
  int hbase = (blk & 15)*8;
  int tid = threadIdx.x;
  int v = tid >> 6, lane = tid & 63;
  int l15 = lane & 15, lhi = lane >> 4;

  // staging coords: wave v stages row sr=v>>2 of each 2-row pass, chunk pair hq=v&3
  int sr = v >> 2;
  int hq = v & 3;
  int g = lane >> 3;                          // chunk rotation (bank spread, R5-verified)
  int w0 = 2*lane, col0 = w0 + 1, col1 = w0 + 2;
  const float* xb = x + ((size_t)b*C_)*HW_;
  // compute coords (R5-verified): row phr, px half pw0, co half mt0
  int phr = v >> 2, pw0 = ((v >> 1) & 1)*64;
  int mt0 = (v & 1)*2;
  const unsigned short* wb = wfrag + (size_t)b*(NT*4*64*8);

  // zero pad cols 0 and 129 of all 6 slots (never overwritten by staging)
  if (tid < 96) {
    int sl = tid >> 4, cc = (tid >> 3) & 1, ch = tid & 7;
    int col = cc ? 129 : 0;
    uint4 zv; zv.x = 0; zv.y = 0; zv.z = 0; zv.w = 0;
    *reinterpret_cast<uint4*>(&xs[(sl*130 + col)*128 + ch*16]) = zv;
  }

  float2 sv[2][8];   // in-flight staged rows (static indexing only)

  // ---- direct stage (prologue): rows gbase+sr -> slots slbase+sr
  auto stage_direct = [&](int gbase, int slbase) {
    int grow = gbase + sr;
    bool valid = (grow >= 0) & (grow < H_);
    int gc = min(max(grow, 0), H_-1);
    const float* xrow = xb + (size_t)gc*W_;
    int sl = slbase + sr;
#pragma unroll
    for (int i = 0; i < 2; ++i) {
      int chunk = (hq*2 + i + g) & 7;
      uint4 o0, o1;
      unsigned short* s0 = reinterpret_cast<unsigned short*>(&o0);
      unsigned short* s1 = reinterpret_cast<unsigned short*>(&o1);
#pragma unroll
      for (int j = 0; j < 8; ++j) {
        float2 f = *reinterpret_cast<const float2*>(xrow + (size_t)(chunk*8 + j)*HW_ + w0);
        s0[j] = valid ? f2bf(f.x) : (unsigned short)0;
        s1[j] = valid ? f2bf(f.y) : (unsigned short)0;
      }
      *reinterpret_cast<uint4*>(&xs[(sl*130 + col0)*128 + (((chunk ^ col0) & 7) << 4)]) = o0;
      *reinterpret_cast<uint4*>(&xs[(sl*130 + col1)*128 + (((chunk ^ col1) & 7) << 4)]) = o1;
    }
  };
  // ---- split stage: issue loads early (unconditional, clamped addr)
  auto stage_issue = [&](int gbase) {
    int grow = gbase + sr;
    int gc = min(max(grow, 0), H_-1);
    const float* xrow = xb + (size_t)gc*W_;
#pragma unroll
    for (int i = 0; i < 2; ++i) {
      int chunk = (hq*2 + i + g) & 7;
#pragma unroll
      for (int j = 0; j < 8; ++j)
        sv[i][j] = *reinterpret_cast<const float2*>(xrow + (size_t)(chunk*8 + j)*HW_ + w0);
    }
  };
  // ---- split stage: commit (cvt + swizzled ds_write), zero for invalid rows
  auto stage_commit = [&](int gbase, int slbase6) {
    int grow = gbase + sr;
    bool valid = (grow >= 0) & (grow < H_);
    int sl = slbase6 + sr; if (sl >= 6) sl -= 6;
#pragma unroll
    for (int i = 0; i < 2; ++i) {
      int chunk = (hq*2 + i + g) & 7;
      uint4 o0, o1;
      unsigned short* s0 = reinterpret_cast<unsigned short*>(&o0);
      unsigned short* s1 = reinterpret_cast<unsigned short*>(&o1);
#pragma unroll
      for (int j = 0; j < 8; ++j) {
        s0[j] = valid ? f2bf(sv[i][j].x) : (unsigned short)0;
        s1[j] = valid ? f2bf(sv[i][j].y) : (unsigned short)0;
      }
      *reinterpret_cast<uint4*>(&xs[(sl*130 + col0)*128 + (((chunk ^ col0) & 7) << 4)]) = o0;
      *reinterpret_cast<uint4*>(&xs[(sl*130 + col1)*128 + (((chunk ^ col1) & 7) << 4)]) = o1;
    }
  };

  // ---- prologue: stage pair-0's 4 rows (hbase-1..hbase+2) into slots 0..3
  stage_direct(hbase - 1, 0);
  stage_direct(hbase + 1, 2);

  short8 wf0 = *reinterpret_cast<const short8*>(wb + (((mt0 + 0)*64 + lane)*8));
  short8 wf1 = *reinterpret_cast<const short8*>(wb + (((mt0 + 1)*64 + lane)*8));
  __syncthreads();

#pragma unroll 1
  for (int p = 0; p < 4; ++p) {
    if (p < 3) stage_issue(hbase + 2*p + 3);   // rows for pair p+1; hides under K-loop

    f32x4 acc[4][2];
#pragma unroll
    for (int mp = 0; mp < 4; ++mp)
#pragma unroll
      for (int nc = 0; nc < 2; ++nc)
        acc[mp][nc] = (f32x4){0.f, 0.f, 0.f, 0.f};

    int rsb = 2*p + phr;   // ring row base (mod 6 applied per access)
#pragma unroll
    for (int t = 0; t < NT; ++t) {
      int kk = t >> 1, kh = kk/3, kw = kk - 3*kh, half = t & 1;
      short8 nf0, nf1;
      if (t + 1 < NT) {                        // weight prefetch depth-1 (L1-hot after pair 0)
        nf0 = *reinterpret_cast<const short8*>(wb + ((((t+1)*4 + mt0 + 0)*64 + lane)*8));
        nf1 = *reinterpret_cast<const short8*>(wb + ((((t+1)*4 + mt0 + 1)*64 + lane)*8));
      }
      int chunk = half*4 + lhi;
      int rs = rsb + kh; if (rs >= 6) rs -= 6;
      short8 xa[4];
#pragma unroll
      for (int mp = 0; mp < 4; ++mp) {
        int col = pw0 + mp*16 + l15 + kw;
        xa[mp] = *reinterpret_cast<const short8*>(&xs[(rs*130 + col)*128 + (((chunk ^ col) & 7) << 4)]);
      }
#pragma unroll
      for (int mp = 0; mp < 4; ++mp) {
        acc[mp][0] = __builtin_amdgcn_mfma_f32_16x16x32_bf16(xa[mp], wf0, acc[mp][0], 0, 0, 0);
        acc[mp][1] = __builtin_amdgcn_mfma_f32_16x16x32_bf16(xa[mp], wf1, acc[mp][1], 0, 0, 0);
      }
      wf0 = nf0; wf1 = nf1;
    }

    // ---- store pair p (R5-verified mapping; direct scattered f32x4 — R10 A/B: pattern-neutral)
    int ph = hbase + 2*p + phr;
#pragma unroll
    for (int nc = 0; nc < 2; ++nc) {
      int co = (mt0 + nc)*16 + l15;
      float* op = out + (((size_t)b*C_ + co)*H_ + ph)*W_;
#pragma unroll
      for (int mp = 0; mp < 4; ++mp)
        *reinterpret_cast<f32x4*>(op + pw0 + mp*16 + lhi*4) = acc[mp][nc];
    }

    if (p < 3) {
      stage_commit(hbase + 2*p + 3, (2*p + 4) % 6);   // slots disjoint from all live readers
      // reload t=0 weight tiles for next pair (L1 hit)
      wf0 = *reinterpret_cast<const short8*>(wb + (((mt0 + 0)*64 + lane)*8));
      wf1 = *reinterpret_cast<const short8*>(wb + (((mt0 + 1)*64 + lane)*8));
    }
    __syncthreads();
  }
}

__global__ void sentinel_k(float* out, int n) {
  int i = blockIdx.x*256 + threadIdx.x;
  if (i < n) out[i] = 1.0e6f;
}

extern "C" void kernel_launch(void* const* d_in, const int* in_sizes, int n_in,
                              void* d_out, int out_size, void* d_ws, size_t ws_size,
                              hipStream_t stream) {
  const float* x  = (const float*)d_in[0];
  const float* z  = (const float*)d_in[1];
  const float* gw = (const float*)d_in[2];
  const float* gb = (const float*)d_in[3];
  float* out = (float*)d_out;

  size_t wfrag_elems = (size_t)B_*IDXN;                   // bf16 elems
  size_t need = wfrag_elems*sizeof(unsigned short);
  if (ws_size < need) {
    sentinel_k<<<(out_size + 255)/256, 256, 0, stream>>>(out, out_size);
    return;
  }
  unsigned short* wfrag = (unsigned short*)d_ws;

  wgen_k <<<IDXN/128, 256, 0, stream>>>(z, gw, gb, wfrag);
  conv_k <<<B_*16, 512, 0, stream>>>(x, wfrag, out);
}